// Round 6
// baseline (252.380 us; speedup 1.0000x reference)
//
#include <hip/hip_runtime.h>

typedef __attribute__((ext_vector_type(8))) short short8;
typedef __attribute__((ext_vector_type(4))) float f32x4;

#define NHEADS 16
#define DK 64
#define SEQ 2048
#define DMODEL 1024

__device__ __forceinline__ unsigned short f2bf(float f) {
  union { float f; unsigned int u; } c; c.f = f;
  unsigned int u = c.u;
  return (unsigned short)((u + 0x7FFFu + ((u >> 16) & 1u)) >> 16);
}

__device__ __forceinline__ float exp2_hw(float x) {
  float y;
  asm("v_exp_f32 %0, %1" : "=v"(y) : "v"(x));
  return y;
}

__device__ __forceinline__ unsigned int cvtpk_bf16(float lo, float hi) {
  unsigned int r;
  asm("v_cvt_pk_bf16_f32 %0, %1, %2" : "=v"(r) : "v"(lo), "v"(hi));
  return r;
}

__device__ __forceinline__ short8 ldg16(const unsigned short* p) {
  return *reinterpret_cast<const short8*>(p);
}

__device__ __forceinline__ void gload_lds16(const unsigned short* g, unsigned short* l) {
  __builtin_amdgcn_global_load_lds(
      (const __attribute__((address_space(1))) unsigned int*)g,
      (__attribute__((address_space(3))) unsigned int*)l, 16, 0, 0);
}

__global__ void cast_qkv(const float* __restrict__ a0, const float* __restrict__ a1,
                         const float* __restrict__ a2, unsigned short* __restrict__ d0,
                         unsigned short* __restrict__ d1, unsigned short* __restrict__ d2) {
  const float* s = blockIdx.y == 0 ? a0 : (blockIdx.y == 1 ? a1 : a2);
  unsigned short* d = blockIdx.y == 0 ? d0 : (blockIdx.y == 1 ? d1 : d2);
  int i = blockIdx.x * blockDim.x + threadIdx.x;
  float4 v = reinterpret_cast<const float4*>(s)[i];
  ushort4 o;
  o.x = f2bf(v.x); o.y = f2bf(v.y); o.z = f2bf(v.z); o.w = f2bf(v.w);
  reinterpret_cast<ushort4*>(d)[i] = o;
}

__global__ void cast_w4(const float* __restrict__ a0, const float* __restrict__ a1,
                        const float* __restrict__ a2, const float* __restrict__ a3,
                        unsigned short* __restrict__ d0, unsigned short* __restrict__ d1,
                        unsigned short* __restrict__ d2, unsigned short* __restrict__ d3) {
  const float* s = blockIdx.y == 0 ? a0 : (blockIdx.y == 1 ? a1 : (blockIdx.y == 2 ? a2 : a3));
  unsigned short* d = blockIdx.y == 0 ? d0 : (blockIdx.y == 1 ? d1 : (blockIdx.y == 2 ? d2 : d3));
  int i = blockIdx.x * blockDim.x + threadIdx.x;
  float4 v = reinterpret_cast<const float4*>(s)[i];
  ushort4 o;
  o.x = f2bf(v.x); o.y = f2bf(v.y); o.z = f2bf(v.z); o.w = f2bf(v.w);
  reinterpret_cast<ushort4*>(d)[i] = o;
}

struct ProjPtrs {
  const unsigned short* A0; const unsigned short* A1; const unsigned short* A2;
  const unsigned short* W0; const unsigned short* W1; const unsigned short* W2;
  const float* bias0; const float* bias1; const float* bias2;
  unsigned short* dst0; unsigned short* dst1; unsigned short* dst2;
};

// ---- projection GEMM: 128x128 tile, 4 waves (64x64 each), BK=32, double-buffered LDS.
// z=0: Q (pre-scaled 1/8*log2e, [B,H,S,64]); z=1: K; z=2: V transposed ([B,H,64,S])
__global__ __launch_bounds__(256) void gemm_proj(ProjPtrs p) {
  __shared__ __align__(16) unsigned short As[2][4096];
  __shared__ __align__(16) unsigned short Bs[2][4096];
  const int mode = blockIdx.z;
  const unsigned short* A = mode == 0 ? p.A0 : (mode == 1 ? p.A1 : p.A2);
  const unsigned short* W = mode == 0 ? p.W0 : (mode == 1 ? p.W1 : p.W2);
  const float* bias = mode == 0 ? p.bias0 : (mode == 1 ? p.bias1 : p.bias2);
  unsigned short* dst = mode == 0 ? p.dst0 : (mode == 1 ? p.dst1 : p.dst2);
  const int m0 = blockIdx.y * 128, n0 = blockIdx.x * 128;
  const int t = threadIdx.x, lane = t & 63, w = t >> 6;
  const int wr = w >> 1, wc = w & 1;
  const int lr = lane >> 4, lc = lane & 15;
  // staging sources: thread owns chunks t and t+256 of each 128x32 tile (chunk = 8 shorts)
  const unsigned short* a_src0 = A + (size_t)(m0 + (t >> 2)) * DMODEL + (t & 3) * 8;
  const unsigned short* a_src1 = A + (size_t)(m0 + 64 + (t >> 2)) * DMODEL + (t & 3) * 8;
  const unsigned short* w_src0 = W + (size_t)(n0 + (t >> 2)) * DMODEL + (t & 3) * 8;
  const unsigned short* w_src1 = W + (size_t)(n0 + 64 + (t >> 2)) * DMODEL + (t & 3) * 8;

  f32x4 acc[4][4] = {};
  // prologue: stage k0=0 into buf 0
  gload_lds16(a_src0, &As[0][t * 8]);
  gload_lds16(a_src1, &As[0][2048 + t * 8]);
  gload_lds16(w_src0, &Bs[0][t * 8]);
  gload_lds16(w_src1, &Bs[0][2048 + t * 8]);
  __syncthreads();
  int buf = 0;
  for (int k0 = 0; k0 < DMODEL; k0 += 32) {
    if (k0 < DMODEL - 32) {
      const int kn = k0 + 32;
      gload_lds16(a_src0 + kn, &As[buf ^ 1][t * 8]);
      gload_lds16(a_src1 + kn, &As[buf ^ 1][2048 + t * 8]);
      gload_lds16(w_src0 + kn, &Bs[buf ^ 1][t * 8]);
      gload_lds16(w_src1 + kn, &Bs[buf ^ 1][2048 + t * 8]);
    }
    short8 a[4], b[4];
#pragma unroll
    for (int i = 0; i < 4; ++i) {
      a[i] = *reinterpret_cast<const short8*>(&As[buf][(wr * 64 + i * 16 + lc) * 32 + lr * 8]);
      b[i] = *reinterpret_cast<const short8*>(&Bs[buf][(wc * 64 + i * 16 + lc) * 32 + lr * 8]);
    }
#pragma unroll
    for (int mi = 0; mi < 4; ++mi)
#pragma unroll
      for (int ni = 0; ni < 4; ++ni)
        acc[mi][ni] = __builtin_amdgcn_mfma_f32_16x16x32_bf16(a[mi], b[ni], acc[mi][ni], 0, 0, 0);
    __syncthreads();
    buf ^= 1;
  }
#pragma unroll
  for (int mi = 0; mi < 4; ++mi) {
#pragma unroll
    for (int ni = 0; ni < 4; ++ni) {
      const int cg = n0 + wc * 64 + ni * 16 + lc;
      const int rb = m0 + wr * 64 + mi * 16 + lr * 4;
      const float bv = bias[cg];
      const int h = cg >> 6, d = cg & 63;
      if (mode == 2) {
        const int bb = rb >> 11, s = rb & 2047;
        ushort4 pk;
        pk.x = f2bf(acc[mi][ni][0] + bv);
        pk.y = f2bf(acc[mi][ni][1] + bv);
        pk.z = f2bf(acc[mi][ni][2] + bv);
        pk.w = f2bf(acc[mi][ni][3] + bv);
        *reinterpret_cast<ushort4*>(dst + (((size_t)((bb * NHEADS + h) * DK + d)) << 11) + s) = pk;
      } else {
        // Q: fold 1/sqrt(64) * log2(e) so softmax runs in exp2 domain
        const float sc = (mode == 0) ? 0.18033688f : 1.0f;
#pragma unroll
        for (int j = 0; j < 4; ++j) {
          const int rg = rb + j;
          const int bb = rg >> 11, s = rg & 2047;
          dst[((size_t)(bb * NHEADS + h) * SEQ + s) * DK + d] = f2bf((acc[mi][ni][j] + bv) * sc);
        }
      }
    }
  }
}

// ---- output GEMM: 128x64 tile, 4 waves (64x32 each), BK=32, double-buffered LDS.
__global__ __launch_bounds__(256) void gemm_out(const unsigned short* __restrict__ A,
                                                const unsigned short* __restrict__ W,
                                                const float* __restrict__ bias,
                                                float* __restrict__ out) {
  __shared__ __align__(16) unsigned short As[2][4096];
  __shared__ __align__(16) unsigned short Bs[2][2048];
  const int m0 = blockIdx.y * 128, n0 = blockIdx.x * 64;
  const int t = threadIdx.x, lane = t & 63, w = t >> 6;
  const int wr = w >> 1, wc = w & 1;
  const int lr = lane >> 4, lc = lane & 15;
  const unsigned short* a_src0 = A + (size_t)(m0 + (t >> 2)) * DMODEL + (t & 3) * 8;
  const unsigned short* a_src1 = A + (size_t)(m0 + 64 + (t >> 2)) * DMODEL + (t & 3) * 8;
  const unsigned short* w_src0 = W + (size_t)(n0 + (t >> 2)) * DMODEL + (t & 3) * 8;

  f32x4 acc[4][2] = {};
  gload_lds16(a_src0, &As[0][t * 8]);
  gload_lds16(a_src1, &As[0][2048 + t * 8]);
  gload_lds16(w_src0, &Bs[0][t * 8]);
  __syncthreads();
  int buf = 0;
  for (int k0 = 0; k0 < DMODEL; k0 += 32) {
    if (k0 < DMODEL - 32) {
      const int kn = k0 + 32;
      gload_lds16(a_src0 + kn, &As[buf ^ 1][t * 8]);
      gload_lds16(a_src1 + kn, &As[buf ^ 1][2048 + t * 8]);
      gload_lds16(w_src0 + kn, &Bs[buf ^ 1][t * 8]);
    }
    short8 a[4], b[2];
#pragma unroll
    for (int i = 0; i < 4; ++i)
      a[i] = *reinterpret_cast<const short8*>(&As[buf][(wr * 64 + i * 16 + lc) * 32 + lr * 8]);
#pragma unroll
    for (int i = 0; i < 2; ++i)
      b[i] = *reinterpret_cast<const short8*>(&Bs[buf][(wc * 32 + i * 16 + lc) * 32 + lr * 8]);
#pragma unroll
    for (int mi = 0; mi < 4; ++mi)
#pragma unroll
      for (int ni = 0; ni < 2; ++ni)
        acc[mi][ni] = __builtin_amdgcn_mfma_f32_16x16x32_bf16(a[mi], b[ni], acc[mi][ni], 0, 0, 0);
    __syncthreads();
    buf ^= 1;
  }
#pragma unroll
  for (int mi = 0; mi < 4; ++mi)
#pragma unroll
    for (int ni = 0; ni < 2; ++ni) {
      const int cg = n0 + wc * 32 + ni * 16 + lc;
      const int rb = m0 + wr * 64 + mi * 16 + lr * 4;
      const float bv = bias[cg];
#pragma unroll
      for (int j = 0; j < 4; ++j)
        out[(size_t)(rb + j) * DMODEL + cg] = acc[mi][ni][j] + bv;
    }
}

// Flash attention: 4 waves/block, 32 q-rows/wave (two 16-row halves), K/V tiles
// double-buffered in LDS via global_load_lds with XOR-swizzle (slot ^= row&7).
__global__ __launch_bounds__(256) void attn_fwd(const unsigned short* __restrict__ Qh,
                                                const unsigned short* __restrict__ Kh,
                                                const unsigned short* __restrict__ Vt,
                                                unsigned short* __restrict__ Oh) {
  __shared__ __align__(16) unsigned short Ktile[2][4096];   // [kv 64][d 64], swizzled
  __shared__ __align__(16) unsigned short Vtile[2][4096];   // [d 64][kv 64], swizzled
  __shared__ __align__(16) unsigned short P[4][32][76];     // per-wave [q][kv], padded
  const int t = threadIdx.x, w = t >> 6, lane = t & 63;
  // XCD swizzle (512 blocks, 8 XCDs): blocks sharing (b,h) land on one XCD's L2
  const int bx = ((blockIdx.x & 7) << 6) | (blockIdx.x >> 3);
  const int bh = bx >> 4, qblk = bx & 15;
  const int q0 = qblk * 128 + w * 32;
  const unsigned short* Qp = Qh + (size_t)bh * SEQ * DK;
  const unsigned short* Kp = Kh + (size_t)bh * SEQ * DK;
  const unsigned short* Vp = Vt + (size_t)bh * DK * SEQ;
  const int r = lane & 15, g = lane >> 4;

  // Q fragments (B-operand): halves A (rows q0..+15) and B (rows q0+16..+31)
  const short8 qa0 = ldg16(Qp + (size_t)(q0 + r) * DK + g * 8);
  const short8 qa1 = ldg16(Qp + (size_t)(q0 + r) * DK + 32 + g * 8);
  const short8 qb0 = ldg16(Qp + (size_t)(q0 + 16 + r) * DK + g * 8);
  const short8 qb1 = ldg16(Qp + (size_t)(q0 + 16 + r) * DK + 32 + g * 8);

  // staging: 512 chunks of 16B per tile; this thread owns chunks c0, c1.
  // LDS linear chunk c = row*8 + slot; source slot = slot ^ (row&7).
  const int c0 = w * 64 + lane, c1 = c0 + 256;
  const int r0 = c0 >> 3, s0 = (c0 & 7) ^ (r0 & 7);
  const int r1 = c1 >> 3, s1 = (c1 & 7) ^ (r1 & 7);
  const unsigned short* ks0 = Kp + r0 * DK + s0 * 8;
  const unsigned short* ks1 = Kp + r1 * DK + s1 * 8;
  const unsigned short* vs0 = Vp + (size_t)r0 * SEQ + s0 * 8;
  const unsigned short* vs1 = Vp + (size_t)r1 * SEQ + s1 * 8;

  float mA = -1e30f, lA = 0.f, mB = -1e30f, lB = 0.f;
  f32x4 oA[4] = {}, oB[4] = {};

  // swizzled read offsets (shorts): k-chunk g -> slot g^(r&7); chunk g+4 -> (g+4)^(r&7)
  const int sw0 = ((g ^ (r & 7)) << 3);
  const int sw1 = (((g + 4) ^ (r & 7)) << 3);
  char* prowA = (char*)&P[w][r][0];
  char* prowB = (char*)&P[w][16 + r][0];

  // prologue: stage tile 0 into buf 0
  gload_lds16(ks0, &Ktile[0][w * 512]);
  gload_lds16(ks1, &Ktile[0][2048 + w * 512]);
  gload_lds16(vs0, &Vtile[0][w * 512]);
  gload_lds16(vs1, &Vtile[0][2048 + w * 512]);
  __syncthreads();

  int buf = 0;
  for (int kt = 0; kt < 32; ++kt) {
    // issue next-tile staging (drained by the barrier at end of this iter)
    if (kt < 31) {
      const int kvn = (kt + 1) * 64;
      gload_lds16(ks0 + kvn * DK, &Ktile[buf ^ 1][w * 512]);
      gload_lds16(ks1 + kvn * DK, &Ktile[buf ^ 1][2048 + w * 512]);
      gload_lds16(vs0 + kvn, &Vtile[buf ^ 1][w * 512]);
      gload_lds16(vs1 + kvn, &Vtile[buf ^ 1][2048 + w * 512]);
    }
    // K fragments from LDS; QK^T swapped: D[kv][q], lane holds q=r, kv=16nt+4g+j
    f32x4 sA[4] = {}, sB[4] = {};
    __builtin_amdgcn_s_setprio(1);
#pragma unroll
    for (int nt = 0; nt < 4; ++nt) {
      const short8 k0 = *reinterpret_cast<const short8*>(&Ktile[buf][(nt * 16 + r) * 64 + sw0]);
      const short8 k1 = *reinterpret_cast<const short8*>(&Ktile[buf][(nt * 16 + r) * 64 + sw1]);
      sA[nt] = __builtin_amdgcn_mfma_f32_16x16x32_bf16(k0, qa0, sA[nt], 0, 0, 0);
      sA[nt] = __builtin_amdgcn_mfma_f32_16x16x32_bf16(k1, qa1, sA[nt], 0, 0, 0);
      sB[nt] = __builtin_amdgcn_mfma_f32_16x16x32_bf16(k0, qb0, sB[nt], 0, 0, 0);
      sB[nt] = __builtin_amdgcn_mfma_f32_16x16x32_bf16(k1, qb1, sB[nt], 0, 0, 0);
    }
    __builtin_amdgcn_s_setprio(0);
    // softmax half A (exp2 domain, defer-max THR=8)
    {
      f32x4 pm;
#pragma unroll
      for (int j = 0; j < 4; ++j)
        pm[j] = fmaxf(fmaxf(sA[0][j], sA[1][j]), fmaxf(sA[2][j], sA[3][j]));
      float pmax = fmaxf(fmaxf(pm[0], pm[1]), fmaxf(pm[2], pm[3]));
      pmax = fmaxf(pmax, __shfl_xor(pmax, 16));
      pmax = fmaxf(pmax, __shfl_xor(pmax, 32));
      if (!__all(pmax - mA <= 8.f)) {
        const float mn = fmaxf(mA, pmax);
        const float al = exp2_hw(mA - mn);
        mA = mn; lA *= al;
        float alj[4];
#pragma unroll
        for (int j = 0; j < 4; ++j) alj[j] = __shfl(al, 4 * g + j, 16);
#pragma unroll
        for (int nt = 0; nt < 4; ++nt)
#pragma unroll
          for (int j = 0; j < 4; ++j) oA[nt][j] *= alj[j];
      }
#pragma unroll
      for (int nt = 0; nt < 4; ++nt)
#pragma unroll
        for (int j = 0; j < 4; ++j) sA[nt][j] = exp2_hw(sA[nt][j] - mA);
      f32x4 s4;
#pragma unroll
      for (int j = 0; j < 4; ++j) s4[j] = (sA[0][j] + sA[1][j]) + (sA[2][j] + sA[3][j]);
      float sum = (s4[0] + s4[1]) + (s4[2] + s4[3]);
      sum += __shfl_xor(sum, 16);
      sum += __shfl_xor(sum, 32);
      lA += sum;
#pragma unroll
      for (int nt = 0; nt < 4; ++nt) {
        uint2 pk;
        pk.x = cvtpk_bf16(sA[nt][0], sA[nt][1]);
        pk.y = cvtpk_bf16(sA[nt][2], sA[nt][3]);
        *reinterpret_cast<uint2*>(prowA + nt * 32 + g * 8) = pk;
      }
    }
    // softmax half B
    {
      f32x4 pm;
#pragma unroll
      for (int j = 0; j < 4; ++j)
        pm[j] = fmaxf(fmaxf(sB[0][j], sB[1][j]), fmaxf(sB[2][j], sB[3][j]));
      float pmax = fmaxf(fmaxf(pm[0], pm[1]), fmaxf(pm[2], pm[3]));
      pmax = fmaxf(pmax, __shfl_xor(pmax, 16));
      pmax = fmaxf(pmax, __shfl_xor(pmax, 32));
      if (!__all(pmax - mB <= 8.f)) {
        const float mn = fmaxf(mB, pmax);
        const float al = exp2_hw(mB - mn);
        mB = mn; lB *= al;
        float alj[4];
#pragma unroll
        for (int j = 0; j < 4; ++j) alj[j] = __shfl(al, 4 * g + j, 16);
#pragma unroll
        for (int nt = 0; nt < 4; ++nt)
#pragma unroll
          for (int j = 0; j < 4; ++j) oB[nt][j] *= alj[j];
      }
#pragma unroll
      for (int nt = 0; nt < 4; ++nt)
#pragma unroll
        for (int j = 0; j < 4; ++j) sB[nt][j] = exp2_hw(sB[nt][j] - mB);
      f32x4 s4;
#pragma unroll
      for (int j = 0; j < 4; ++j) s4[j] = (sB[0][j] + sB[1][j]) + (sB[2][j] + sB[3][j]);
      float sum = (s4[0] + s4[1]) + (s4[2] + s4[3]);
      sum += __shfl_xor(sum, 16);
      sum += __shfl_xor(sum, 32);
      lB += sum;
#pragma unroll
      for (int nt = 0; nt < 4; ++nt) {
        uint2 pk;
        pk.x = cvtpk_bf16(sB[nt][0], sB[nt][1]);
        pk.y = cvtpk_bf16(sB[nt][2], sB[nt][3]);
        *reinterpret_cast<uint2*>(prowB + nt * 32 + g * 8) = pk;
      }
    }
    // P fragments (per-wave LDS; compiler inserts lgkmcnt)
    union { short8 v; unsigned long long q[2]; } pA0, pA1, pB0, pB1;
    pA0.q[0] = *reinterpret_cast<const unsigned long long*>(prowA + g * 16);
    pA0.q[1] = *reinterpret_cast<const unsigned long long*>(prowA + g * 16 + 8);
    pA1.q[0] = *reinterpret_cast<const unsigned long long*>(prowA + 64 + g * 16);
    pA1.q[1] = *reinterpret_cast<const unsigned long long*>(prowA + 64 + g * 16 + 8);
    pB0.q[0] = *reinterpret_cast<const unsigned long long*>(prowB + g * 16);
    pB0.q[1] = *reinterpret_cast<const unsigned long long*>(prowB + g * 16 + 8);
    pB1.q[0] = *reinterpret_cast<const unsigned long long*>(prowB + 64 + g * 16);
    pB1.q[1] = *reinterpret_cast<const unsigned long long*>(prowB + 64 + g * 16 + 8);
    // V fragments + PV
    __builtin_amdgcn_s_setprio(1);
#pragma unroll
    for (int nt = 0; nt < 4; ++nt) {
      const short8 v0 = *reinterpret_cast<const short8*>(&Vtile[buf][(nt * 16 + r) * 64 + sw0]);
      const short8 v1 = *reinterpret_cast<const short8*>(&Vtile[buf][(nt * 16 + r) * 64 + sw1]);
      oA[nt] = __builtin_amdgcn_mfma_f32_16x16x32_bf16(pA0.v, v0, oA[nt], 0, 0, 0);
      oA[nt] = __builtin_amdgcn_mfma_f32_16x16x32_bf16(pA1.v, v1, oA[nt], 0, 0, 0);
      oB[nt] = __builtin_amdgcn_mfma_f32_16x16x32_bf16(pB0.v, v0, oB[nt], 0, 0, 0);
      oB[nt] = __builtin_amdgcn_mfma_f32_16x16x32_bf16(pB1.v, v1, oB[nt], 0, 0, 0);
    }
    __builtin_amdgcn_s_setprio(0);
    __syncthreads();  // drains next-tile staging (vmcnt) + protects buffer swap
    buf ^= 1;
  }

  const float invA = 1.f / lA, invB = 1.f / lB;
  float ivA[4], ivB[4];
#pragma unroll
  for (int j = 0; j < 4; ++j) {
    ivA[j] = __shfl(invA, 4 * g + j, 16);
    ivB[j] = __shfl(invB, 4 * g + j, 16);
  }
  const size_t ob = ((size_t)((bh >> 4) * SEQ + q0)) * DMODEL + (size_t)(bh & 15) * DK;
#pragma unroll
  for (int nt = 0; nt < 4; ++nt)
#pragma unroll
    for (int j = 0; j < 4; ++j) {
      Oh[ob + (size_t)(g * 4 + j) * DMODEL + nt * 16 + r] = f2bf(oA[nt][j] * ivA[j]);
      Oh[ob + (size_t)(16 + g * 4 + j) * DMODEL + nt * 16 + r] = f2bf(oB[nt][j] * ivB[j]);
    }
}

extern "C" void kernel_launch(void* const* d_in, const int* in_sizes, int n_in,
                              void* d_out, int out_size, void* d_ws, size_t ws_size,
                              hipStream_t stream) {
  const float* q   = (const float*)d_in[0];
  const float* k   = (const float*)d_in[1];
  const float* v   = (const float*)d_in[2];
  const float* w_q = (const float*)d_in[3];
  const float* b_q = (const float*)d_in[4];
  const float* w_k = (const float*)d_in[5];
  const float* b_k = (const float*)d_in[6];
  const float* w_v = (const float*)d_in[7];
  const float* b_v = (const float*)d_in[8];
  const float* w_o = (const float*)d_in[9];
  const float* b_o = (const float*)d_in[10];
  float* out = (float*)d_out;
  char* ws = (char*)d_ws;
  const size_t MB = (size_t)1 << 20;
  unsigned short* qc  = (unsigned short*)(ws + 0 * MB);
  unsigned short* kc  = (unsigned short*)(ws + 8 * MB);
  unsigned short* vc  = (unsigned short*)(ws + 16 * MB);
  unsigned short* wqc = (unsigned short*)(ws + 24 * MB);
  unsigned short* wkc = (unsigned short*)(ws + 26 * MB);
  unsigned short* wvc = (unsigned short*)(ws + 28 * MB);
  unsigned short* woc = (unsigned short*)(ws + 30 * MB);
  unsigned short* Qh  = (unsigned short*)(ws + 32 * MB);
  unsigned short* Kh  = (unsigned short*)(ws + 40 * MB);
  unsigned short* Vt  = (unsigned short*)(ws + 48 * MB);
  unsigned short* Oh  = (unsigned short*)(ws + 56 * MB);

  cast_qkv<<<dim3(4096, 3), 256, 0, stream>>>(q, k, v, qc, kc, vc);
  cast_w4<<<dim3(1024, 4), 256, 0, stream>>>(w_q, w_k, w_v, w_o, wqc, wkc, wvc, woc);

  ProjPtrs p;
  p.A0 = qc; p.A1 = kc; p.A2 = vc;
  p.W0 = wqc; p.W1 = wkc; p.W2 = wvc;
  p.bias0 = b_q; p.bias1 = b_k; p.bias2 = b_v;
  p.dst0 = Qh; p.dst1 = Kh; p.dst2 = Vt;
  gemm_proj<<<dim3(8, 32, 3), 256, 0, stream>>>(p);

  attn_fwd<<<512, 256, 0, stream>>>(Qh, Kh, Vt, Oh);

  gemm_out<<<dim3(16, 32), 256, 0, stream>>>(Oh, woc, b_o, out);
}

// Round 8
// 240.497 us; speedup vs baseline: 1.0494x; 1.0494x over previous
//
#include <hip/hip_runtime.h>

typedef __attribute__((ext_vector_type(8))) short short8;
typedef __attribute__((ext_vector_type(4))) float f32x4;

#define NHEADS 16
#define DK 64
#define SEQ 2048
#define DMODEL 1024

__device__ __forceinline__ unsigned short f2bf(float f) {
  union { float f; unsigned int u; } c; c.f = f;
  unsigned int u = c.u;
  return (unsigned short)((u + 0x7FFFu + ((u >> 16) & 1u)) >> 16);
}

__device__ __forceinline__ float exp2_hw(float x) {
  float y;
  asm("v_exp_f32 %0, %1" : "=v"(y) : "v"(x));
  return y;
}

__device__ __forceinline__ unsigned int cvtpk_bf16(float lo, float hi) {
  unsigned int r;
  asm("v_cvt_pk_bf16_f32 %0, %1, %2" : "=v"(r) : "v"(lo), "v"(hi));
  return r;
}

__device__ __forceinline__ short8 ldg16(const unsigned short* p) {
  return *reinterpret_cast<const short8*>(p);
}

__device__ __forceinline__ void gload_lds16(const unsigned short* g, unsigned short* l) {
  __builtin_amdgcn_global_load_lds(
      (const __attribute__((address_space(1))) unsigned int*)g,
      (__attribute__((address_space(3))) unsigned int*)l, 16, 0, 0);
}

struct CastPtrs {
  const float* s0; const float* s1; const float* s2; const float* s3;
  const float* s4; const float* s5; const float* s6;
  unsigned short* d0; unsigned short* d1; unsigned short* d2; unsigned short* d3;
  unsigned short* d4; unsigned short* d5; unsigned short* d6;
};

// one launch: 3x4096 blocks for q/k/v (4.19M elems each), 4x1024 for weights (1.05M each)
__global__ void cast_all(CastPtrs c) {
  const int b = blockIdx.x;
  const float* s; unsigned short* d; int off;
  if (b < 4096)        { s = c.s0; d = c.d0; off = b; }
  else if (b < 8192)   { s = c.s1; d = c.d1; off = b - 4096; }
  else if (b < 12288)  { s = c.s2; d = c.d2; off = b - 8192; }
  else if (b < 13312)  { s = c.s3; d = c.d3; off = b - 12288; }
  else if (b < 14336)  { s = c.s4; d = c.d4; off = b - 13312; }
  else if (b < 15360)  { s = c.s5; d = c.d5; off = b - 14336; }
  else                 { s = c.s6; d = c.d6; off = b - 15360; }
  const int i = off * 256 + threadIdx.x;
  float4 v = reinterpret_cast<const float4*>(s)[i];
  ushort4 o;
  o.x = f2bf(v.x); o.y = f2bf(v.y); o.z = f2bf(v.z); o.w = f2bf(v.w);
  reinterpret_cast<ushort4*>(d)[i] = o;
}

struct ProjPtrs {
  const unsigned short* A0; const unsigned short* A1; const unsigned short* A2;
  const unsigned short* W0; const unsigned short* W1; const unsigned short* W2;
  const float* bias0; const float* bias1; const float* bias2;
  unsigned short* dst0; unsigned short* dst1; unsigned short* dst2;
};

// ---- projection GEMM: 128x128 tile, 4 waves, BK=32, triple-buffered LDS with
// counted vmcnt. sched_barrier(0) pins: s_barrier is IntrNoMem, so without the
// pins LLVM may hoist ds_reads / global_load_lds across it (R7 race).
__global__ __launch_bounds__(256) void gemm_proj(ProjPtrs p) {
  __shared__ __align__(16) unsigned short S[24576];  // A bufs [3][4096] @0, B bufs [3][4096] @12288
  const int mode = blockIdx.z;
  const unsigned short* A = mode == 0 ? p.A0 : (mode == 1 ? p.A1 : p.A2);
  const unsigned short* W = mode == 0 ? p.W0 : (mode == 1 ? p.W1 : p.W2);
  const float* bias = mode == 0 ? p.bias0 : (mode == 1 ? p.bias1 : p.bias2);
  unsigned short* dst = mode == 0 ? p.dst0 : (mode == 1 ? p.dst1 : p.dst2);
  const int m0 = blockIdx.y * 128, n0 = blockIdx.x * 128;
  const int t = threadIdx.x, lane = t & 63, w = t >> 6;
  const int wr = w >> 1, wc = w & 1;
  const int lr = lane >> 4, lc = lane & 15;
  const unsigned short* a_src0 = A + (size_t)(m0 + (t >> 2)) * DMODEL + (t & 3) * 8;
  const unsigned short* a_src1 = a_src0 + (size_t)64 * DMODEL;
  const unsigned short* w_src0 = W + (size_t)(n0 + (t >> 2)) * DMODEL + (t & 3) * 8;
  const unsigned short* w_src1 = w_src0 + (size_t)64 * DMODEL;

  f32x4 acc[4][4] = {};

#define PSTAGE(s, bi) do { \
    gload_lds16(a_src0 + (s) * 32, S + (bi) * 4096 + t * 8); \
    gload_lds16(a_src1 + (s) * 32, S + (bi) * 4096 + 2048 + t * 8); \
    gload_lds16(w_src0 + (s) * 32, S + 12288 + (bi) * 4096 + t * 8); \
    gload_lds16(w_src1 + (s) * 32, S + 12288 + (bi) * 4096 + 2048 + t * 8); } while (0)

  auto compute = [&](const int bi) {
    const unsigned short* Ab = S + bi * 4096;
    const unsigned short* Bb = S + 12288 + bi * 4096;
    short8 a[4], b[4];
#pragma unroll
    for (int i = 0; i < 4; ++i) {
      a[i] = *reinterpret_cast<const short8*>(Ab + (wr * 64 + i * 16 + lc) * 32 + lr * 8);
      b[i] = *reinterpret_cast<const short8*>(Bb + (wc * 64 + i * 16 + lc) * 32 + lr * 8);
    }
#pragma unroll
    for (int mi = 0; mi < 4; ++mi)
#pragma unroll
      for (int ni = 0; ni < 4; ++ni)
        acc[mi][ni] = __builtin_amdgcn_mfma_f32_16x16x32_bf16(a[mi], b[ni], acc[mi][ni], 0, 0, 0);
  };

  PSTAGE(0, 0);
  PSTAGE(1, 1);
  for (int k = 0; k < 30; ++k) {
    PSTAGE(k + 2, (k + 2) % 3);
    asm volatile("s_waitcnt vmcnt(8)" ::: "memory");
    __builtin_amdgcn_s_barrier();
    __builtin_amdgcn_sched_barrier(0);
    compute(k % 3);
    __builtin_amdgcn_sched_barrier(0);
    __builtin_amdgcn_s_barrier();
    __builtin_amdgcn_sched_barrier(0);
  }
  asm volatile("s_waitcnt vmcnt(4)" ::: "memory");
  __builtin_amdgcn_s_barrier();
  __builtin_amdgcn_sched_barrier(0);
  compute(0);
  __builtin_amdgcn_sched_barrier(0);
  __builtin_amdgcn_s_barrier();
  __builtin_amdgcn_sched_barrier(0);
  asm volatile("s_waitcnt vmcnt(0)" ::: "memory");
  __builtin_amdgcn_s_barrier();
  __builtin_amdgcn_sched_barrier(0);
  compute(1);

  if (mode == 2) {
    // V: transpose 64x64 wave tile through LDS -> contiguous 128B row-segment stores
    __syncthreads();  // all waves done reading staging bufs before reuse
    unsigned short* T = S + w * 4608;  // 64 rows x stride 72
    const int h = (n0 + wc * 64) >> 6;
    const int rb0 = m0 + wr * 64;
    const int bb = rb0 >> 11, s_base = rb0 & 2047;
#pragma unroll
    for (int mi = 0; mi < 4; ++mi) {
#pragma unroll
      for (int ni = 0; ni < 4; ++ni) {
        const float bv = bias[n0 + wc * 64 + ni * 16 + lc];
        uint2 pk;
        pk.x = cvtpk_bf16(acc[mi][ni][0] + bv, acc[mi][ni][1] + bv);
        pk.y = cvtpk_bf16(acc[mi][ni][2] + bv, acc[mi][ni][3] + bv);
        *reinterpret_cast<uint2*>(&T[(ni * 16 + lc) * 72 + mi * 16 + lr * 4]) = pk;
      }
    }
    __builtin_amdgcn_sched_barrier(0);
    unsigned short* dstb = dst + ((size_t)(bb * NHEADS + h) * 64) * 2048 + s_base;
#pragma unroll
    for (int i = 0; i < 8; ++i) {
      const int drow = i * 8 + (lane >> 3), scol = (lane & 7) * 8;
      const short8 val = *reinterpret_cast<const short8*>(&T[drow * 72 + scol]);
      *reinterpret_cast<short8*>(dstb + (size_t)drow * 2048 + scol) = val;
    }
  } else {
    const float sc = (mode == 0) ? 0.18033688f : 1.0f;  // 1/8 * log2(e) for exp2-domain softmax
#pragma unroll
    for (int mi = 0; mi < 4; ++mi) {
#pragma unroll
      for (int ni = 0; ni < 4; ++ni) {
        const int cg = n0 + wc * 64 + ni * 16 + lc;
        const int rb = m0 + wr * 64 + mi * 16 + lr * 4;
        const float bv = bias[cg];
        const int h = cg >> 6, d = cg & 63;
#pragma unroll
        for (int j = 0; j < 4; ++j) {
          const int rg = rb + j;
          const int bb = rg >> 11, s = rg & 2047;
          dst[((size_t)(bb * NHEADS + h) * SEQ + s) * DK + d] = f2bf((acc[mi][ni][j] + bv) * sc);
        }
      }
    }
  }
}

// ---- output GEMM: 128x64 tile, 4 waves (64x32 each), BK=32, triple-buffered counted-vmcnt.
__global__ __launch_bounds__(256) void gemm_out(const unsigned short* __restrict__ A,
                                                const unsigned short* __restrict__ W,
                                                const float* __restrict__ bias,
                                                float* __restrict__ out) {
  __shared__ __align__(16) unsigned short S[18432];  // A bufs [3][4096] @0, B bufs [3][2048] @12288
  const int m0 = blockIdx.y * 128, n0 = blockIdx.x * 64;
  const int t = threadIdx.x, lane = t & 63, w = t >> 6;
  const int wr = w >> 1, wc = w & 1;
  const int lr = lane >> 4, lc = lane & 15;
  const unsigned short* a_src0 = A + (size_t)(m0 + (t >> 2)) * DMODEL + (t & 3) * 8;
  const unsigned short* a_src1 = a_src0 + (size_t)64 * DMODEL;
  const unsigned short* w_src0 = W + (size_t)(n0 + (t >> 2)) * DMODEL + (t & 3) * 8;

  f32x4 acc[4][2] = {};

#define OSTAGE(s, bi) do { \
    gload_lds16(a_src0 + (s) * 32, S + (bi) * 4096 + t * 8); \
    gload_lds16(a_src1 + (s) * 32, S + (bi) * 4096 + 2048 + t * 8); \
    gload_lds16(w_src0 + (s) * 32, S + 12288 + (bi) * 2048 + t * 8); } while (0)

  auto compute = [&](const int bi) {
    const unsigned short* Ab = S + bi * 4096;
    const unsigned short* Bb = S + 12288 + bi * 2048;
    short8 a[4], b[2];
#pragma unroll
    for (int i = 0; i < 4; ++i)
      a[i] = *reinterpret_cast<const short8*>(Ab + (wr * 64 + i * 16 + lc) * 32 + lr * 8);
#pragma unroll
    for (int i = 0; i < 2; ++i)
      b[i] = *reinterpret_cast<const short8*>(Bb + (wc * 32 + i * 16 + lc) * 32 + lr * 8);
#pragma unroll
    for (int mi = 0; mi < 4; ++mi)
#pragma unroll
      for (int ni = 0; ni < 2; ++ni)
        acc[mi][ni] = __builtin_amdgcn_mfma_f32_16x16x32_bf16(a[mi], b[ni], acc[mi][ni], 0, 0, 0);
  };

  OSTAGE(0, 0);
  OSTAGE(1, 1);
  for (int k = 0; k < 30; ++k) {
    OSTAGE(k + 2, (k + 2) % 3);
    asm volatile("s_waitcnt vmcnt(6)" ::: "memory");
    __builtin_amdgcn_s_barrier();
    __builtin_amdgcn_sched_barrier(0);
    compute(k % 3);
    __builtin_amdgcn_sched_barrier(0);
    __builtin_amdgcn_s_barrier();
    __builtin_amdgcn_sched_barrier(0);
  }
  asm volatile("s_waitcnt vmcnt(3)" ::: "memory");
  __builtin_amdgcn_s_barrier();
  __builtin_amdgcn_sched_barrier(0);
  compute(0);
  __builtin_amdgcn_sched_barrier(0);
  __builtin_amdgcn_s_barrier();
  __builtin_amdgcn_sched_barrier(0);
  asm volatile("s_waitcnt vmcnt(0)" ::: "memory");
  __builtin_amdgcn_s_barrier();
  __builtin_amdgcn_sched_barrier(0);
  compute(1);

#pragma unroll
  for (int mi = 0; mi < 4; ++mi)
#pragma unroll
    for (int ni = 0; ni < 2; ++ni) {
      const int cg = n0 + wc * 32 + ni * 16 + lc;
      const int rb = m0 + wr * 64 + mi * 16 + lr * 4;
      const float bv = bias[cg];
#pragma unroll
      for (int j = 0; j < 4; ++j)
        out[(size_t)(rb + j) * DMODEL + cg] = acc[mi][ni][j] + bv;
    }
}

// Flash attention: unchanged (79 µs anchor).
__global__ __launch_bounds__(256) void attn_fwd(const unsigned short* __restrict__ Qh,
                                                const unsigned short* __restrict__ Kh,
                                                const unsigned short* __restrict__ Vt,
                                                unsigned short* __restrict__ Oh) {
  __shared__ __align__(16) unsigned short Ktile[2][4096];   // [kv 64][d 64], swizzled
  __shared__ __align__(16) unsigned short Vtile[2][4096];   // [d 64][kv 64], swizzled
  __shared__ __align__(16) unsigned short P[4][32][76];     // per-wave [q][kv], padded
  const int t = threadIdx.x, w = t >> 6, lane = t & 63;
  const int bx = ((blockIdx.x & 7) << 6) | (blockIdx.x >> 3);
  const int bh = bx >> 4, qblk = bx & 15;
  const int q0 = qblk * 128 + w * 32;
  const unsigned short* Qp = Qh + (size_t)bh * SEQ * DK;
  const unsigned short* Kp = Kh + (size_t)bh * SEQ * DK;
  const unsigned short* Vp = Vt + (size_t)bh * DK * SEQ;
  const int r = lane & 15, g = lane >> 4;

  const short8 qa0 = ldg16(Qp + (size_t)(q0 + r) * DK + g * 8);
  const short8 qa1 = ldg16(Qp + (size_t)(q0 + r) * DK + 32 + g * 8);
  const short8 qb0 = ldg16(Qp + (size_t)(q0 + 16 + r) * DK + g * 8);
  const short8 qb1 = ldg16(Qp + (size_t)(q0 + 16 + r) * DK + 32 + g * 8);

  const int c0 = w * 64 + lane, c1 = c0 + 256;
  const int r0 = c0 >> 3, s0 = (c0 & 7) ^ (r0 & 7);
  const int r1 = c1 >> 3, s1 = (c1 & 7) ^ (r1 & 7);
  const unsigned short* ks0 = Kp + r0 * DK + s0 * 8;
  const unsigned short* ks1 = Kp + r1 * DK + s1 * 8;
  const unsigned short* vs0 = Vp + (size_t)r0 * SEQ + s0 * 8;
  const unsigned short* vs1 = Vp + (size_t)r1 * SEQ + s1 * 8;

  float mA = -1e30f, lA = 0.f, mB = -1e30f, lB = 0.f;
  f32x4 oA[4] = {}, oB[4] = {};

  const int sw0 = ((g ^ (r & 7)) << 3);
  const int sw1 = (((g + 4) ^ (r & 7)) << 3);
  char* prowA = (char*)&P[w][r][0];
  char* prowB = (char*)&P[w][16 + r][0];

  gload_lds16(ks0, &Ktile[0][w * 512]);
  gload_lds16(ks1, &Ktile[0][2048 + w * 512]);
  gload_lds16(vs0, &Vtile[0][w * 512]);
  gload_lds16(vs1, &Vtile[0][2048 + w * 512]);
  __syncthreads();

  int buf = 0;
  for (int kt = 0; kt < 32; ++kt) {
    if (kt < 31) {
      const int kvn = (kt + 1) * 64;
      gload_lds16(ks0 + kvn * DK, &Ktile[buf ^ 1][w * 512]);
      gload_lds16(ks1 + kvn * DK, &Ktile[buf ^ 1][2048 + w * 512]);
      gload_lds16(vs0 + kvn, &Vtile[buf ^ 1][w * 512]);
      gload_lds16(vs1 + kvn, &Vtile[buf ^ 1][2048 + w * 512]);
    }
    f32x4 sA[4] = {}, sB[4] = {};
    __builtin_amdgcn_s_setprio(1);
#pragma unroll
    for (int nt = 0; nt < 4; ++nt) {
      const short8 k0 = *reinterpret_cast<const short8*>(&Ktile[buf][(nt * 16 + r) * 64 + sw0]);
      const short8 k1 = *reinterpret_cast<const short8*>(&Ktile[buf][(nt * 16 + r) * 64 + sw1]);
      sA[nt] = __builtin_amdgcn_mfma_f32_16x16x32_bf16(k0, qa0, sA[nt], 0, 0, 0);
      sA[nt] = __builtin_amdgcn_mfma_f32_16x16x32_bf16(k1, qa1, sA[nt], 0, 0, 0);
      sB[nt] = __builtin_amdgcn_mfma_f32_16x16x32_bf16(k0, qb0, sB[nt], 0, 0, 0);
      sB[nt] = __builtin_amdgcn_mfma_f32_16x16x32_bf16(k1, qb1, sB[nt], 0, 0, 0);
    }
    __builtin_amdgcn_s_setprio(0);
    {
      f32x4 pm;
#pragma unroll
      for (int j = 0; j < 4; ++j)
        pm[j] = fmaxf(fmaxf(sA[0][j], sA[1][j]), fmaxf(sA[2][j], sA[3][j]));
      float pmax = fmaxf(fmaxf(pm[0], pm[1]), fmaxf(pm[2], pm[3]));
      pmax = fmaxf(pmax, __shfl_xor(pmax, 16));
      pmax = fmaxf(pmax, __shfl_xor(pmax, 32));
      if (!__all(pmax - mA <= 8.f)) {
        const float mn = fmaxf(mA, pmax);
        const float al = exp2_hw(mA - mn);
        mA = mn; lA *= al;
        float alj[4];
#pragma unroll
        for (int j = 0; j < 4; ++j) alj[j] = __shfl(al, 4 * g + j, 16);
#pragma unroll
        for (int nt = 0; nt < 4; ++nt)
#pragma unroll
          for (int j = 0; j < 4; ++j) oA[nt][j] *= alj[j];
      }
#pragma unroll
      for (int nt = 0; nt < 4; ++nt)
#pragma unroll
        for (int j = 0; j < 4; ++j) sA[nt][j] = exp2_hw(sA[nt][j] - mA);
      f32x4 s4;
#pragma unroll
      for (int j = 0; j < 4; ++j) s4[j] = (sA[0][j] + sA[1][j]) + (sA[2][j] + sA[3][j]);
      float sum = (s4[0] + s4[1]) + (s4[2] + s4[3]);
      sum += __shfl_xor(sum, 16);
      sum += __shfl_xor(sum, 32);
      lA += sum;
#pragma unroll
      for (int nt = 0; nt < 4; ++nt) {
        uint2 pk;
        pk.x = cvtpk_bf16(sA[nt][0], sA[nt][1]);
        pk.y = cvtpk_bf16(sA[nt][2], sA[nt][3]);
        *reinterpret_cast<uint2*>(prowA + nt * 32 + g * 8) = pk;
      }
    }
    {
      f32x4 pm;
#pragma unroll
      for (int j = 0; j < 4; ++j)
        pm[j] = fmaxf(fmaxf(sB[0][j], sB[1][j]), fmaxf(sB[2][j], sB[3][j]));
      float pmax = fmaxf(fmaxf(pm[0], pm[1]), fmaxf(pm[2], pm[3]));
      pmax = fmaxf(pmax, __shfl_xor(pmax, 16));
      pmax = fmaxf(pmax, __shfl_xor(pmax, 32));
      if (!__all(pmax - mB <= 8.f)) {
        const float mn = fmaxf(mB, pmax);
        const float al = exp2_hw(mB - mn);
        mB = mn; lB *= al;
        float alj[4];
#pragma unroll
        for (int j = 0; j < 4; ++j) alj[j] = __shfl(al, 4 * g + j, 16);
#pragma unroll
        for (int nt = 0; nt < 4; ++nt)
#pragma unroll
          for (int j = 0; j < 4; ++j) oB[nt][j] *= alj[j];
      }
#pragma unroll
      for (int nt = 0; nt < 4; ++nt)
#pragma unroll
        for (int j = 0; j < 4; ++j) sB[nt][j] = exp2_hw(sB[nt][j] - mB);
      f32x4 s4;
#pragma unroll
      for (int j = 0; j < 4; ++j) s4[j] = (sB[0][j] + sB[1][j]) + (sB[2][j] + sB[3][j]);
      float sum = (s4[0] + s4[1]) + (s4[2] + s4[3]);
      sum += __shfl_xor(sum, 16);
      sum += __shfl_xor(sum, 32);
      lB += sum;
#pragma unroll
      for (int nt = 0; nt < 4; ++nt) {
        uint2 pk;
        pk.x = cvtpk_bf16(sB[nt][0], sB[nt][1]);
        pk.y = cvtpk_bf16(sB[nt][2], sB[nt][3]);
        *reinterpret_cast<uint2*>(prowB + nt * 32 + g * 8) = pk;
      }
    }
    union { short8 v; unsigned long long q[2]; } pA0, pA1, pB0, pB1;
    pA0.q[0] = *reinterpret_cast<const unsigned long long*>(prowA + g * 16);
    pA0.q[1] = *reinterpret_cast<const unsigned long long*>(prowA + g * 16 + 8);
    pA1.q[0] = *reinterpret_cast<const unsigned long long*>(prowA + 64 + g * 16);
    pA1.q[1] = *reinterpret_cast<const unsigned long long*>(prowA + 64 + g * 16 + 8);
    pB0.q[0] = *reinterpret_cast<const unsigned long long*>(prowB + g * 16);
    pB0.q[1] = *reinterpret_cast<const unsigned long long*>(prowB + g * 16 + 8);
    pB1.q[0] = *reinterpret_cast<const unsigned long long*>(prowB + 64 + g * 16);
    pB1.q[1] = *reinterpret_cast<const unsigned long long*>(prowB + 64 + g * 16 + 8);
    __builtin_amdgcn_s_setprio(1);
#pragma unroll
    for (int nt = 0; nt < 4; ++nt) {
      const short8 v0 = *reinterpret_cast<const short8*>(&Vtile[buf][(nt * 16 + r) * 64 + sw0]);
      const short8 v1 = *reinterpret_cast<const short8*>(&Vtile[buf][(nt * 16 + r) * 64 + sw1]);
      oA[nt] = __builtin_amdgcn_mfma_f32_16x16x32_bf16(pA0.v, v0, oA[nt], 0, 0, 0);
      oA[nt] = __builtin_amdgcn_mfma_f32_16x16x32_bf16(pA1.v, v1, oA[nt], 0, 0, 0);
      oB[nt] = __builtin_amdgcn_mfma_f32_16x16x32_bf16(pB0.v, v0, oB[nt], 0, 0, 0);
      oB[nt] = __builtin_amdgcn_mfma_f32_16x16x32_bf16(pB1.v, v1, oB[nt], 0, 0, 0);
    }
    __builtin_amdgcn_s_setprio(0);
    __syncthreads();
    buf ^= 1;
  }

  const float invA = 1.f / lA, invB = 1.f / lB;
  float ivA[4], ivB[4];
#pragma unroll
  for (int j = 0; j < 4; ++j) {
    ivA[j] = __shfl(invA, 4 * g + j, 16);
    ivB[j] = __shfl(invB, 4 * g + j, 16);
  }
  const size_t ob = ((size_t)((bh >> 4) * SEQ + q0)) * DMODEL + (size_t)(bh & 15) * DK;
#pragma unroll
  for (int nt = 0; nt < 4; ++nt)
#pragma unroll
    for (int j = 0; j < 4; ++j) {
      Oh[ob + (size_t)(g * 4 + j) * DMODEL + nt * 16 + r] = f2bf(oA[nt][j] * ivA[j]);
      Oh[ob + (size_t)(16 + g * 4 + j) * DMODEL + nt * 16 + r] = f2bf(oB[nt][j] * ivB[j]);
    }
}

extern "C" void kernel_launch(void* const* d_in, const int* in_sizes, int n_in,
                              void* d_out, int out_size, void* d_ws, size_t ws_size,
                              hipStream_t stream) {
  const float* q   = (const float*)d_in[0];
  const float* k   = (const float*)d_in[1];
  const float* v   = (const float*)d_in[2];
  const float* w_q = (const float*)d_in[3];
  const float* b_q = (const float*)d_in[4];
  const float* w_k = (const float*)d_in[5];
  const float* b_k = (const float*)d_in[6];
  const float* w_v = (const float*)d_in[7];
  const float* b_v = (const float*)d_in[8];
  const float* w_o = (const float*)d_in[9];
  const float* b_o = (const float*)d_in[10];
  float* out = (float*)d_out;
  char* ws = (char*)d_ws;
  const size_t MB = (size_t)1 << 20;
  unsigned short* qc  = (unsigned short*)(ws + 0 * MB);
  unsigned short* kc  = (unsigned short*)(ws + 8 * MB);
  unsigned short* vc  = (unsigned short*)(ws + 16 * MB);
  unsigned short* wqc = (unsigned short*)(ws + 24 * MB);
  unsigned short* wkc = (unsigned short*)(ws + 26 * MB);
  unsigned short* wvc = (unsigned short*)(ws + 28 * MB);
  unsigned short* woc = (unsigned short*)(ws + 30 * MB);
  unsigned short* Qh  = (unsigned short*)(ws + 32 * MB);
  unsigned short* Kh  = (unsigned short*)(ws + 40 * MB);
  unsigned short* Vt  = (unsigned short*)(ws + 48 * MB);
  unsigned short* Oh  = (unsigned short*)(ws + 56 * MB);

  CastPtrs cp;
  cp.s0 = q; cp.s1 = k; cp.s2 = v; cp.s3 = w_q; cp.s4 = w_k; cp.s5 = w_v; cp.s6 = w_o;
  cp.d0 = qc; cp.d1 = kc; cp.d2 = vc; cp.d3 = wqc; cp.d4 = wkc; cp.d5 = wvc; cp.d6 = woc;
  cast_all<<<16384, 256, 0, stream>>>(cp);

  ProjPtrs p;
  p.A0 = qc; p.A1 = kc; p.A2 = vc;
  p.W0 = wqc; p.W1 = wkc; p.W2 = wvc;
  p.bias0 = b_q; p.bias1 = b_k; p.bias2 = b_v;
  p.dst0 = Qh; p.dst1 = Kh; p.dst2 = Vt;
  gemm_proj<<<dim3(8, 32, 3), 256, 0, stream>>>(p);

  attn_fwd<<<512, 256, 0, stream>>>(Qh, Kh, Vt, Oh);

  gemm_out<<<dim3(16, 32), 256, 0, stream>>>(Oh, woc, b_o, out);
}